// Round 18
// baseline (99.835 us; speedup 1.0000x reference)
//
#include <hip/hip_runtime.h>
#include <stdint.h>

// RNN1: B=4096,T=256,E=27,H=64.
// a_{t+1} = tanh(a_t @ Waa^T + x_t @ Wax^T + ba), x_t = word[:,t-1,:] (0 at t=0)
// y[:,t,:] = a_{t+1} @ Wy^T + by
//
// Round 18 = r17 (87us, 4-wave hidden split) with the exchange critical path
// shortened:
//  1. ROTATED loop: state ds_read at STEP top; its ~120cyc latency filled
//     with sF-independent work (x pack, zp MFMA, xc prefetch). Reads are
//     compiler-visible (compiler inserts minimal lgkmcnt before first use).
//  2. Conflict-free exchange layout sxc[buf][wv][lg][p16][2]: wave writes
//     128 contiguous words (b64), reads are 4 contiguous-across-wave b64 ->
//     0 conflicts (was 8-way aliased: lg-stride = 0 mod 32). Word order
//     identical to r17's sigma mapping -> numerics unchanged.
//  3. Parallel state-MFMA pair (pa || pb, f32 add): dep 156 -> ~86 cyc.
//  4. Staging + y-flush distributed across all 4 waves (wave w owns step
//     ts+w; 2 chunks/lane) -> no wave-0/2 barrier-skew spikes.
// Cross-wave handoffs (xs, ys, sxc) all barrier-separated; double-buffered
// sxc uses the r2-validated discipline (reader's retire -> its barrier ->
// writer's next-buffer write).

#define B_ 4096
#define T_ 256
#define E_ 27
#define H_ 64
#define WROW_ (H_ + E_)  // 91

typedef _Float16 f16x8 __attribute__((ext_vector_type(8)));
typedef float f32x4 __attribute__((ext_vector_type(4)));
typedef unsigned int u32x4 __attribute__((ext_vector_type(4)));
typedef unsigned int u32x2 __attribute__((ext_vector_type(2)));

struct __attribute__((packed)) f4a { float v[4]; };  // 4B-aligned global float4

// RNE f32->f16 pair pack (state + weight prep; r12-validated numerics).
static __device__ __forceinline__ unsigned pkf16(float a, float b) {
  _Float16 ha = (_Float16)a, hb = (_Float16)b;
  unsigned short ua = __builtin_bit_cast(unsigned short, ha);
  unsigned short ub = __builtin_bit_cast(unsigned short, hb);
  return (unsigned)ua | ((unsigned)ub << 16);
}
// RTZ packed f32x2->f16x2 (x-path ONLY; r14 lesson: never biased rounding
// on the recurrent state).
static __device__ __forceinline__ unsigned pkrtz(float a, float b) {
  unsigned r;
  asm("v_cvt_pkrtz_f16_f32 %0, %1, %2" : "=v"(r) : "v"(a), "v"(b));
  return r;
}
static __device__ __forceinline__ float fast_tanh(float z) {
  // tanh(z) = 1 - 2/(exp(2z)+1); exp->inf / ->0 limits give +/-1 correctly
  float e = __expf(2.0f * z);
  float r = __builtin_amdgcn_rcpf(e + 1.0f);
  return __builtin_fmaf(-2.0f, r, 1.0f);
}
static __device__ __forceinline__ f32x4 MFH(u32x4 a, u32x4 b, f32x4 c) {
  return __builtin_amdgcn_mfma_f32_16x16x32_f16(
      __builtin_bit_cast(f16x8, a), __builtin_bit_cast(f16x8, b), c, 0, 0, 0);
}

__global__ __launch_bounds__(256)
__attribute__((amdgpu_waves_per_eu(1, 1))) void rnn_fused(
    const float* __restrict__ word, const float* __restrict__ Wa,
    const float* __restrict__ ba, const float* __restrict__ Wy,
    const float* __restrict__ by, float* __restrict__ out) {
  __shared__ __align__(16) float xs[8][16][36];   // x ring (cols 28..35 = 0)
  __shared__ __align__(16) float ys[16][16][36];  // y ring, 16 slots
  __shared__ __align__(8) unsigned int sxc[2][4][4][16][2];  // state exchange

  const int tid = threadIdx.x;
  const int wv = tid >> 6;    // wave = hidden tile [16wv,16wv+16) + duty step
  const int lane = tid & 63;
  const int p16 = lane & 15;  // batch row within block (n) / A-row (m)
  const int lg = lane >> 4;   // k-slot group / chunk selector for duties
  const int rb = (int)blockIdx.x * 16;

  const float* const wbase = word + (size_t)(rb + p16) * (T_ * E_);
  float* const obase = out + (size_t)(rb + p16) * (T_ * E_);

  // zero xs (slot 0 = x_0 = 0) and sxc (buffer 1 read at t=0)
  for (int i = tid; i < 8 * 16 * 36; i += 256) (&xs[0][0][0])[i] = 0.f;
  for (int i = tid; i < 2 * 4 * 4 * 16 * 2; i += 256)
    (&sxc[0][0][0][0][0])[i] = 0u;

  // ---- per-wave weight fragments (f16), pre-permuted by sigma (r17) ----
  u32x4 WH0, WH1, WXw, WY0, WY1;
  f32x4 BAv, BYv;
  {
    const float* base = Wa + (16 * wv + p16) * WROW_;
#pragma unroll
    for (int v = 0; v < 4; ++v) {
      const int j = 2 * v;
      const int c0 = (j < 4) ? (4 * lg + j) : (12 + 4 * lg + j);
      WH0[v] = pkf16(base[c0], base[c0 + 1]);
      WH1[v] = pkf16(base[c0 + 32], base[c0 + 33]);
      const int e0 = 8 * lg + j, e1 = e0 + 1;  // Wax natural k
      const float w0 = (e0 < E_) ? base[H_ + e0] : 0.f;
      const float w1 = (e1 < E_) ? base[H_ + e1] : 0.f;
      WXw[v] = pkf16(w0, w1);
    }
  }
  {
    const int e = 16 * (wv & 1) + p16;  // Wy rows (waves 0,1 use; 2,3 dead)
    const bool valid = (e < E_);
    const float* rp = Wy + e * H_;
#pragma unroll
    for (int v = 0; v < 4; ++v) {
      const int j = 2 * v;
      const int c0 = (j < 4) ? (4 * lg + j) : (12 + 4 * lg + j);
      WY0[v] = pkf16(valid ? rp[c0] : 0.f, valid ? rp[c0 + 1] : 0.f);
      WY1[v] = pkf16(valid ? rp[c0 + 32] : 0.f, valid ? rp[c0 + 33] : 0.f);
    }
  }
#pragma unroll
  for (int r = 0; r < 4; ++r) BAv[r] = ba[16 * wv + 4 * lg + r];
#pragma unroll
  for (int r = 0; r < 4; ++r) {
    const int e = 16 * (wv & 1) + 4 * lg + r;
    BYv[r] = (e < E_) ? by[e] : 0.f;
  }

  // ---- x staging: wave wv owns step ts+wv; lane covers row p16, chunks
  // {2lg, 2lg+1} (lg=3: chunk 6 only). Double-buffered Rg (r9 discipline).
  // Max load offset (st_-1)*27+24+7 <= 254*27+31 = 6889 < 6912: in-row. ----
  f32x4 Rg[2][2];
#define X_ISSUE(ts, P)                                                      \
  {                                                                         \
    const int st_ = (ts) + wv;                                              \
    if (st_ >= 1 && st_ < T_) {                                             \
      const float* p_ = wbase + (st_ - 1) * E_;                             \
      asm volatile("global_load_dwordx4 %0, %1, off"                        \
                   : "=v"(Rg[P][0]) : "v"(p_ + 8 * lg) : "memory");         \
      if (lg < 3)                                                           \
        asm volatile("global_load_dwordx4 %0, %1, off"                      \
                     : "=v"(Rg[P][1]) : "v"(p_ + 8 * lg + 4) : "memory");   \
    }                                                                       \
  }
#define X_WRITE(ts, P)                                                      \
  {                                                                         \
    asm volatile("s_waitcnt vmcnt(0)" ::: "memory");                        \
    __builtin_amdgcn_sched_barrier(0);                                      \
    const int st_ = (ts) + wv;                                              \
    if (st_ >= 1 && st_ < T_) {                                             \
      float* d_ = &xs[st_ & 7][p16][0];                                     \
      *(f32x4*)(d_ + 8 * lg) = Rg[P][0];                                    \
      if (lg < 3) *(f32x4*)(d_ + 8 * lg + 4) = Rg[P][1];                    \
    }                                                                       \
    asm volatile("s_waitcnt lgkmcnt(0)" ::: "memory");                      \
    __builtin_amdgcn_sched_barrier(0);                                      \
  }
  // y flush: wave wv flushes step tb+wv; lane covers row p16, chunks
  // {2lg, 2lg+1} (lg=3: 3-float tail). Exactly 27 floats, no overrun.
#define Y_FLUSH(tb)                                                         \
  {                                                                         \
    const int s_t = (tb) + wv;                                              \
    const float* s_ = &ys[s_t & 15][p16][0];                                \
    float* d_ = obase + (size_t)s_t * E_;                                   \
    if (lg < 3) {                                                           \
      f32x4 v0_ = *(const f32x4*)(s_ + 8 * lg);                             \
      f32x4 v1_ = *(const f32x4*)(s_ + 8 * lg + 4);                         \
      f4a o0_, o1_;                                                         \
      o0_.v[0] = v0_[0]; o0_.v[1] = v0_[1];                                 \
      o0_.v[2] = v0_[2]; o0_.v[3] = v0_[3];                                 \
      o1_.v[0] = v1_[0]; o1_.v[1] = v1_[1];                                 \
      o1_.v[2] = v1_[2]; o1_.v[3] = v1_[3];                                 \
      *(f4a*)(d_ + 8 * lg) = o0_;                                           \
      *(f4a*)(d_ + 8 * lg + 4) = o1_;                                       \
    } else {                                                                \
      d_[24] = s_[24]; d_[25] = s_[25]; d_[26] = s_[26];                    \
    }                                                                       \
  }

  // ---- prologue: issue steps 0..3 (step 0 skipped: zeros), memset visible,
  // write slots 1..3, issue 4..7, preload xc = x_1 ----
  X_ISSUE(0, 0);
  __syncthreads();
  X_WRITE(0, 0);
  X_ISSUE(4, 1);
  __syncthreads();
  f32x4 xc0, xc1;
  {
    const float* xp = &xs[1][p16][8 * lg];
    xc0 = *(const f32x4*)xp;
    xc1 = *(const f32x4*)(xp + 4);
  }

  // ---- loop-carried: zp = ba + WX*x_t (x_0 = 0 -> ba) ----
  f32x4 zp = BAv;
  const f32x4 zf4 = {0.f, 0.f, 0.f, 0.f};

#define STEP(t)                                                               \
  {                                                                           \
    /* 1) read exchanged state a_t (buffer (t+1)&1; t=0 reads zeros) */       \
    const u32x2 r0_ = *(const u32x2*)&sxc[((t) + 1) & 1][0][lg][p16][0];      \
    const u32x2 r1_ = *(const u32x2*)&sxc[((t) + 1) & 1][1][lg][p16][0];      \
    const u32x2 r2_ = *(const u32x2*)&sxc[((t) + 1) & 1][2][lg][p16][0];      \
    const u32x2 r3_ = *(const u32x2*)&sxc[((t) + 1) & 1][3][lg][p16][0];      \
    /* 2) fill read latency: pack x_{t+1}, zp for t+1, prefetch x_{t+2} */    \
    u32x4 xfn;                                                                \
    xfn[0] = pkrtz(xc0[0], xc0[1]);                                           \
    xfn[1] = pkrtz(xc0[2], xc0[3]);                                           \
    xfn[2] = pkrtz(xc1[0], xc1[1]);                                           \
    xfn[3] = pkrtz(xc1[2], xc1[3]);                                           \
    const f32x4 zpn_ = MFH(WXw, xfn, BAv);                                    \
    if ((t) + 2 < T_) {                                                       \
      const float* xp_ = &xs[((t) + 2) & 7][p16][8 * lg];                     \
      xc0 = *(const f32x4*)xp_;                                               \
      xc1 = *(const f32x4*)(xp_ + 4);                                         \
    }                                                                         \
    /* 3) assemble frags (compiler inserts minimal lgkm wait) */              \
    u32x4 sF0_, sF1_;                                                         \
    sF0_[0] = r0_[0]; sF0_[1] = r0_[1]; sF0_[2] = r1_[0]; sF0_[3] = r1_[1];   \
    sF1_[0] = r2_[0]; sF1_[1] = r2_[1]; sF1_[2] = r3_[0]; sF1_[3] = r3_[1];   \
    /* 4) parallel state-MFMA pair; y (old state) fills the shadow */         \
    const f32x4 pa_ = MFH(WH0, sF0_, zp);                                     \
    const f32x4 pb_ = MFH(WH1, sF1_, zf4);                                    \
    if (wv < 2) {                                                             \
      const f32x4 yv_ = MFH(WY1, sF1_, MFH(WY0, sF0_, BYv));                  \
      *(f32x4*)&ys[((t) + 15) & 15][p16][(wv & 1) * 16 + 4 * lg] = yv_;       \
    }                                                                         \
    const f32x4 d_ = pa_ + pb_;                                               \
    /* 5) tanh + RNE pack -> exchange write (buffer t&1) */                   \
    const float t0_ = fast_tanh(d_[0]);                                       \
    const float t1_ = fast_tanh(d_[1]);                                       \
    const float t2_ = fast_tanh(d_[2]);                                       \
    const float t3_ = fast_tanh(d_[3]);                                       \
    u32x2 pk_;                                                                \
    pk_[0] = pkf16(t0_, t1_);                                                 \
    pk_[1] = pkf16(t2_, t3_);                                                 \
    *(u32x2*)&sxc[(t) & 1][wv][lg][p16][0] = pk_;                             \
    zp = zpn_;                                                                \
    asm volatile("s_waitcnt lgkmcnt(0)" ::: "memory");                        \
    __builtin_amdgcn_sched_barrier(0);                                        \
    __builtin_amdgcn_s_barrier();                                             \
    __builtin_amdgcn_sched_barrier(0);                                        \
  }

#define GROUP(t0, PW, PI)                                                     \
  {                                                                           \
    asm volatile("" : "+a"(WH0), "+a"(WH1), "+a"(WXw), "+a"(WY0), "+a"(WY1)); \
    asm volatile("" : "+v"(BAv), "+v"(BYv));                                  \
    X_WRITE((t0) + 4, PW); /* stage steps t0+4..t0+7 (issued last group) */   \
    X_ISSUE((t0) + 8, PI); /* issue next group into the OTHER buffer */       \
    if ((t0) >= 8) Y_FLUSH((t0)-8); /* flush steps t0-8..t0-5 */              \
    STEP(t0);                                                                 \
    STEP((t0) + 1);                                                           \
    STEP((t0) + 2);                                                           \
    STEP((t0) + 3);                                                           \
  }

  for (int t0 = 0; t0 < T_; t0 += 8) {
    GROUP(t0, 1, 0);      // write R1 (issued in prologue / prev odd group)
    GROUP(t0 + 4, 0, 1);  // write R0, issue R1
  }
  // ---- epilogue: y_255 from final state a_256 (buffer 1), then flush ----
  if (wv < 2) {
    const u32x2 r0_ = *(const u32x2*)&sxc[1][0][lg][p16][0];
    const u32x2 r1_ = *(const u32x2*)&sxc[1][1][lg][p16][0];
    const u32x2 r2_ = *(const u32x2*)&sxc[1][2][lg][p16][0];
    const u32x2 r3_ = *(const u32x2*)&sxc[1][3][lg][p16][0];
    u32x4 sF0_, sF1_;
    sF0_[0] = r0_[0]; sF0_[1] = r0_[1]; sF0_[2] = r1_[0]; sF0_[3] = r1_[1];
    sF1_[0] = r2_[0]; sF1_[1] = r2_[1]; sF1_[2] = r3_[0]; sF1_[3] = r3_[1];
    const f32x4 yv_ = MFH(WY1, sF1_, MFH(WY0, sF0_, BYv));
    *(f32x4*)&ys[15][p16][(wv & 1) * 16 + 4 * lg] = yv_;
  }
  asm volatile("s_waitcnt lgkmcnt(0)" ::: "memory");
  __builtin_amdgcn_s_barrier();
  Y_FLUSH(T_ - 8);
  Y_FLUSH(T_ - 4);
#undef GROUP
#undef STEP
#undef X_ISSUE
#undef X_WRITE
#undef Y_FLUSH
}

extern "C" void kernel_launch(void* const* d_in, const int* in_sizes, int n_in,
                              void* d_out, int out_size, void* d_ws,
                              size_t ws_size, hipStream_t stream) {
  const float* word = (const float*)d_in[0];
  const float* Wa = (const float*)d_in[1];
  const float* ba = (const float*)d_in[2];
  const float* Wy = (const float*)d_in[3];
  const float* by = (const float*)d_in[4];
  float* out = (float*)d_out;
  rnn_fused<<<dim3(B_ / 16), dim3(256), 0, stream>>>(word, Wa, ba, Wy, by, out);
}

// Round 19
// 87.178 us; speedup vs baseline: 1.1452x; 1.1452x over previous
//
#include <hip/hip_runtime.h>
#include <stdint.h>

// RNN1: B=4096,T=256,E=27,H=64.
// a_{t+1} = tanh(a_t @ Waa^T + x_t @ Wax^T + ba), x_t = word[:,t-1,:] (0 at t=0)
// y[:,t,:] = a_{t+1} @ Wy^T + by
//
// Round 19 = r17 (87us, 4-wave hidden split, passing) + two surgical fixes
// (r18's bundle regressed to 100us: y moved onto the read path + same-wave
// vmcnt/store coupling; reverted):
//  1. Exchange layout sxr[buf][wv][lane][2]: writer wave wv lane l writes 8B
//     at [wv][l] (banks 2l mod 32: 2-way = free); consumer lane l reads
//     4x ds_read_b64 at [0..3][l] (same free pattern). Pairing identical to
//     r17's sigma mapping -> numerics bit-identical. Was 8-way aliased.
//  2. Duty balance: y -> waves 2,3 (OLD-state regs, off-path, r17-style);
//     flush -> wave 1; staging stays wave 0. (r17: wave0 = staging+y was
//     the barrier-pacing wave.)
//
// TRANSPOSED 4-wave design (r17): wave w owns hidden tile [16w,16w+16) x 16
// batch rows; per step: 2 chained state MFMAs + 8 trans + zp MFMA; state
// exchange via LDS, one barrier/step, double-buffered. f16 single-term state
// (r12 numerics); RNE state pack (r14: never biased rounding in recurrence).

#define B_ 4096
#define T_ 256
#define E_ 27
#define H_ 64
#define WROW_ (H_ + E_)  // 91

typedef _Float16 f16x8 __attribute__((ext_vector_type(8)));
typedef float f32x4 __attribute__((ext_vector_type(4)));
typedef unsigned int u32x4 __attribute__((ext_vector_type(4)));
typedef unsigned int u32x2 __attribute__((ext_vector_type(2)));

struct __attribute__((packed)) f4a { float v[4]; };  // 4B-aligned global float4

// RNE f32->f16 pair pack (state + weight prep; r12-validated numerics).
static __device__ __forceinline__ unsigned pkf16(float a, float b) {
  _Float16 ha = (_Float16)a, hb = (_Float16)b;
  unsigned short ua = __builtin_bit_cast(unsigned short, ha);
  unsigned short ub = __builtin_bit_cast(unsigned short, hb);
  return (unsigned)ua | ((unsigned)ub << 16);
}
// RTZ packed f32x2->f16x2 (x-path ONLY; r14 lesson).
static __device__ __forceinline__ unsigned pkrtz(float a, float b) {
  unsigned r;
  asm("v_cvt_pkrtz_f16_f32 %0, %1, %2" : "=v"(r) : "v"(a), "v"(b));
  return r;
}
static __device__ __forceinline__ float fast_tanh(float z) {
  // tanh(z) = 1 - 2/(exp(2z)+1); exp->inf / ->0 limits give +/-1 correctly
  float e = __expf(2.0f * z);
  float r = __builtin_amdgcn_rcpf(e + 1.0f);
  return __builtin_fmaf(-2.0f, r, 1.0f);
}
static __device__ __forceinline__ f32x4 MFH(u32x4 a, u32x4 b, f32x4 c) {
  return __builtin_amdgcn_mfma_f32_16x16x32_f16(
      __builtin_bit_cast(f16x8, a), __builtin_bit_cast(f16x8, b), c, 0, 0, 0);
}

__global__ __launch_bounds__(256)
__attribute__((amdgpu_waves_per_eu(1, 1))) void rnn_fused(
    const float* __restrict__ word, const float* __restrict__ Wa,
    const float* __restrict__ ba, const float* __restrict__ Wy,
    const float* __restrict__ by, float* __restrict__ out) {
  __shared__ __align__(16) float xs[8][16][36];   // x ring (cols 28..35 = 0)
  __shared__ __align__(16) float ys[16][16][36];  // y ring, 16 slots
  __shared__ __align__(8) unsigned int sxr[2][4][64][2];  // state exchange

  const int tid = threadIdx.x;
  const int wv = tid >> 6;    // wave = hidden tile [16wv,16wv+16) + duty
  const int lane = tid & 63;
  const int p16 = lane & 15;  // batch row within block (n) / A-row (m)
  const int lg = lane >> 4;   // k-slot group / step-selector for duties
  const int rb = (int)blockIdx.x * 16;

  const float* const wbase = word + (size_t)(rb + p16) * (T_ * E_);
  float* const obase = out + (size_t)(rb + p16) * (T_ * E_);

  // zero xs (slot 0 = x_0 = 0) and sxr
  for (int i = tid; i < 8 * 16 * 36; i += 256) (&xs[0][0][0])[i] = 0.f;
  for (int i = tid; i < 2 * 4 * 64 * 2; i += 256) (&sxr[0][0][0][0])[i] = 0u;

  // ---- per-wave weight fragments (f16), pre-permuted by sigma (r17) ----
  u32x4 WH0, WH1, WXw, WY0, WY1;
  f32x4 BAv, BYv;
  {
    const float* base = Wa + (16 * wv + p16) * WROW_;
#pragma unroll
    for (int v = 0; v < 4; ++v) {
      const int j = 2 * v;
      const int c0 = (j < 4) ? (4 * lg + j) : (12 + 4 * lg + j);
      WH0[v] = pkf16(base[c0], base[c0 + 1]);
      WH1[v] = pkf16(base[c0 + 32], base[c0 + 33]);
      const int e0 = 8 * lg + j, e1 = e0 + 1;  // Wax natural k
      const float w0 = (e0 < E_) ? base[H_ + e0] : 0.f;
      const float w1 = (e1 < E_) ? base[H_ + e1] : 0.f;
      WXw[v] = pkf16(w0, w1);
    }
  }
  {
    const int e = 16 * (wv & 1) + p16;  // Wy rows (waves 2,3 use; 0,1 dead)
    const bool valid = (e < E_);
    const float* rp = Wy + e * H_;
#pragma unroll
    for (int v = 0; v < 4; ++v) {
      const int j = 2 * v;
      const int c0 = (j < 4) ? (4 * lg + j) : (12 + 4 * lg + j);
      WY0[v] = pkf16(valid ? rp[c0] : 0.f, valid ? rp[c0 + 1] : 0.f);
      WY1[v] = pkf16(valid ? rp[c0 + 32] : 0.f, valid ? rp[c0 + 33] : 0.f);
    }
  }
#pragma unroll
  for (int r = 0; r < 4; ++r) BAv[r] = ba[16 * wv + 4 * lg + r];
#pragma unroll
  for (int r = 0; r < 4; ++r) {
    const int e = 16 * (wv & 1) + 4 * lg + r;
    BYv[r] = (e < E_) ? by[e] : 0.f;
  }

  // ---- x staging (wave 0 only; r9/r17-validated, double-buffered regs):
  // lane owns step ts+lg (word row ts+lg-1), 7 float4 chunks. Max offset
  // 254*27+28+3 = 6889 < 6912: stays within this batch row's T*E. ----
  f32x4 Rg[2][7];
#define X_ISSUE(ts, P)                                                      \
  {                                                                         \
    const int st_ = (ts) + lg;                                              \
    if (st_ >= 1 && st_ < T_) {                                             \
      const float* p_ = wbase + (st_ - 1) * E_;                             \
      _Pragma("unroll") for (int c = 0; c < 7; ++c) {                       \
        asm volatile("global_load_dwordx4 %0, %1, off"                      \
                     : "=v"(Rg[P][c]) : "v"(p_ + 4 * c) : "memory");        \
      }                                                                     \
    }                                                                       \
  }
#define X_WRITE(ts, P)                                                      \
  {                                                                         \
    asm volatile("s_waitcnt vmcnt(0)" ::: "memory");                        \
    __builtin_amdgcn_sched_barrier(0);                                      \
    const int st_ = (ts) + lg;                                              \
    if (st_ >= 1 && st_ < T_) {                                             \
      float* d_ = &xs[st_ & 7][p16][0];                                     \
      _Pragma("unroll") for (int c = 0; c < 7; ++c)                         \
        *(f32x4*)(d_ + 4 * c) = Rg[P][c];                                   \
    }                                                                       \
    asm volatile("s_waitcnt lgkmcnt(0)" ::: "memory");                      \
    __builtin_amdgcn_sched_barrier(0);                                      \
  }
#define Y_FLUSH(tb)                                                         \
  {                                                                         \
    const float* s_ = &ys[((tb) + lg) & 15][p16][0];                        \
    float* d_ = obase + (size_t)((tb) + lg) * E_;                           \
    _Pragma("unroll") for (int c = 0; c < 6; ++c) {                         \
      f32x4 v_ = *(const f32x4*)(s_ + 4 * c);                               \
      f4a o_;                                                               \
      o_.v[0] = v_[0]; o_.v[1] = v_[1]; o_.v[2] = v_[2]; o_.v[3] = v_[3];   \
      *(f4a*)(d_ + 4 * c) = o_;                                             \
    }                                                                       \
    f32x4 v6_ = *(const f32x4*)(s_ + 24);                                   \
    d_[24] = v6_[0]; d_[25] = v6_[1]; d_[26] = v6_[2];                      \
  }

  // ---- prologue: wave 0 stages slots 1..3, issues 4..7; preload xc = x_1 --
  if (wv == 0) X_ISSUE(0, 0);
  __syncthreads();
  if (wv == 0) { X_WRITE(0, 0); X_ISSUE(4, 1); }
  __syncthreads();
  f32x4 xc0, xc1;
  {
    const float* xp = &xs[1][p16][8 * lg];
    xc0 = *(const f32x4*)xp;
    xc1 = *(const f32x4*)(xp + 4);
  }

  // ---- loop-carried: sF = a_t (f16 sigma B-frags); zp = ba + WX*x_t ----
  u32x4 sF0 = {0u, 0u, 0u, 0u}, sF1 = sF0;
  f32x4 zp = BAv;

#define STEP(t)                                                               \
  {                                                                           \
    /* critical: 2 chained MFMAs -> tanh x4 -> pack -> exchange */            \
    f32x4 d_ = MFH(WH0, sF0, zp);                                             \
    d_ = MFH(WH1, sF1, d_);                                                   \
    /* off-path (MFMA shadow): y_{t-1} on OLD sF regs (waves 2,3) */          \
    if (wv >= 2) {                                                            \
      f32x4 yv = MFH(WY1, sF1, MFH(WY0, sF0, BYv));                           \
      *(f32x4*)&ys[((t) + 15) & 15][p16][(wv & 1) * 16 + 4 * lg] = yv;        \
    }                                                                         \
    /* zp for step t+1 (xfn = x_{t+1}); then prefetch x_{t+2} */              \
    u32x4 xfn;                                                                \
    xfn[0] = pkrtz(xc0[0], xc0[1]);                                           \
    xfn[1] = pkrtz(xc0[2], xc0[3]);                                           \
    xfn[2] = pkrtz(xc1[0], xc1[1]);                                           \
    xfn[3] = pkrtz(xc1[2], xc1[3]);                                           \
    zp = MFH(WXw, xfn, BAv);                                                  \
    if ((t) + 2 < T_) {                                                       \
      const float* xp_ = &xs[((t) + 2) & 7][p16][8 * lg];                     \
      xc0 = *(const f32x4*)xp_;                                               \
      xc1 = *(const f32x4*)(xp_ + 4);                                         \
    }                                                                         \
    /* tanh (8 trans on THIS SIMD) + RNE pack + exchange write */             \
    const float t0_ = fast_tanh(d_[0]);                                       \
    const float t1_ = fast_tanh(d_[1]);                                       \
    const float t2_ = fast_tanh(d_[2]);                                       \
    const float t3_ = fast_tanh(d_[3]);                                       \
    u32x2 pk_;                                                                \
    pk_[0] = pkf16(t0_, t1_);                                                 \
    pk_[1] = pkf16(t2_, t3_);                                                 \
    *(u32x2*)&sxr[(t) & 1][wv][lane][0] = pk_;                                \
    asm volatile("s_waitcnt lgkmcnt(0)" ::: "memory");                        \
    __builtin_amdgcn_sched_barrier(0);                                        \
    __builtin_amdgcn_s_barrier();                                             \
    __builtin_amdgcn_sched_barrier(0);                                        \
    /* read back full new state: 4 conflict-free b64 (banks 2*lane) */        \
    const u32x2 q0 = *(const u32x2*)&sxr[(t) & 1][0][lane][0];                \
    const u32x2 q1 = *(const u32x2*)&sxr[(t) & 1][1][lane][0];                \
    const u32x2 q2 = *(const u32x2*)&sxr[(t) & 1][2][lane][0];                \
    const u32x2 q3 = *(const u32x2*)&sxr[(t) & 1][3][lane][0];                \
    sF0[0] = q0[0]; sF0[1] = q0[1]; sF0[2] = q1[0]; sF0[3] = q1[1];           \
    sF1[0] = q2[0]; sF1[1] = q2[1]; sF1[2] = q3[0]; sF1[3] = q3[1];           \
  }

#define GROUP(t0, PW, PI)                                                     \
  {                                                                           \
    asm volatile("" : "+a"(WH0), "+a"(WH1), "+a"(WXw), "+a"(WY0), "+a"(WY1)); \
    asm volatile("" : "+v"(BAv), "+v"(BYv));                                  \
    if (wv == 0) { X_WRITE((t0) + 4, PW); X_ISSUE((t0) + 8, PI); }            \
    if (wv == 1 && (t0) >= 8) Y_FLUSH((t0)-8);                                \
    STEP(t0);                                                                 \
    STEP((t0) + 1);                                                           \
    STEP((t0) + 2);                                                           \
    STEP((t0) + 3);                                                           \
  }

  for (int t0 = 0; t0 < T_; t0 += 8) {
    GROUP(t0, 1, 0);      // write R1 (issued in prologue / prev odd group)
    GROUP(t0 + 4, 0, 1);  // write R0, issue R1
  }
  // ---- epilogue: y_255 from final state (carried regs), then flush ----
  if (wv >= 2) {
    f32x4 yv = MFH(WY1, sF1, MFH(WY0, sF0, BYv));
    *(f32x4*)&ys[15][p16][(wv & 1) * 16 + 4 * lg] = yv;
  }
  asm volatile("s_waitcnt lgkmcnt(0)" ::: "memory");
  __builtin_amdgcn_s_barrier();
  if (wv == 1) {
    Y_FLUSH(T_ - 8);
    Y_FLUSH(T_ - 4);
  }
#undef GROUP
#undef STEP
#undef X_ISSUE
#undef X_WRITE
#undef Y_FLUSH
}

extern "C" void kernel_launch(void* const* d_in, const int* in_sizes, int n_in,
                              void* d_out, int out_size, void* d_ws,
                              size_t ws_size, hipStream_t stream) {
  const float* word = (const float*)d_in[0];
  const float* Wa = (const float*)d_in[1];
  const float* ba = (const float*)d_in[2];
  const float* Wy = (const float*)d_in[3];
  const float* by = (const float*)d_in[4];
  float* out = (float*)d_out;
  rnn_fused<<<dim3(B_ / 16), dim3(256), 0, stream>>>(word, Wa, ba, Wy, by, out);
}